// Round 5
// baseline (666.361 us; speedup 1.0000x reference)
//
#include <hip/hip_runtime.h>
#include <math.h>

#define Bb 64
#define Tt 512
#define Dd 1536
#define Hh 30
#define NC 128            // packed GX cols: gate layout unchanged
#define Mm (Bb*Tt)        // 32768 rows
#define KSTEPS 48         // 1536 / 32

typedef unsigned short u16;
typedef __attribute__((ext_vector_type(8))) short short8v;  // 8 bf16 = 4 VGPRs
typedef __attribute__((ext_vector_type(4))) float f32x4;

__device__ __forceinline__ float rcpf_(float x) { return __builtin_amdgcn_rcpf(x); }
__device__ __forceinline__ float sigmoidf_(float x) {
    return rcpf_(1.f + __expf(-x));
}
__device__ __forceinline__ float tanhf_fast(float x) {
    float e = __expf(2.f * x);
    return fmaf(-2.f, rcpf_(e + 1.f), 1.f);
}
__device__ __forceinline__ float softplus_(float x) {
    return fmaxf(x, 0.f) + __logf(1.f + __expf(-fabsf(x)));
}
__device__ __forceinline__ float rl_f(float v, int lane) {
    return __uint_as_float(__builtin_amdgcn_readlane(__float_as_uint(v), lane));
}

// DPP quad_perm broadcast within each 4-lane group (pure VALU, ~4 cyc):
// CTRL 0x55 = all lanes read quad-lane 1, 0xAA -> lane 2, 0xFF -> lane 3.
#define QPERM(src, CTRL) \
    __uint_as_float((unsigned)__builtin_amdgcn_mov_dpp((int)__float_as_uint(src), CTRL, 0xF, 0xF, false))

__device__ __forceinline__ f32x4 mm_bf16(short8v a, short8v b, f32x4 c) {
    return __builtin_amdgcn_mfma_f32_16x16x32_bf16(a, b, c, 0, 0, 0);
}

union U4S8 { unsigned int u[4]; short8v s; };

// exact hi/lo split: x = hi + lo with hi = trunc-bf16(x)
__device__ __forceinline__ void cvt_split(const float4 a, const float4 b,
                                          short8v& hi, short8v& lo) {
    float x[8] = {a.x, a.y, a.z, a.w, b.x, b.y, b.z, b.w};
    U4S8 H, L;
#pragma unroll
    for (int i = 0; i < 4; i++) {
        unsigned int u0 = __float_as_uint(x[2 * i]);
        unsigned int u1 = __float_as_uint(x[2 * i + 1]);
        unsigned int h0 = u0 & 0xffff0000u;
        unsigned int h1 = u1 & 0xffff0000u;
        H.u[i] = (u0 >> 16) | h1;
        float l0 = x[2 * i]     - __uint_as_float(h0);
        float l1 = x[2 * i + 1] - __uint_as_float(h1);
        L.u[i] = (__float_as_uint(l0) >> 16) | (__float_as_uint(l1) & 0xffff0000u);
    }
    hi = H.s;
    lo = L.s;
}

// ---------------- pack 1: W -> bf16 hi/lo, col-major Wb*[c][k] ----------------
__global__ __launch_bounds__(256) void pack_w(const float* __restrict__ Wih,
                                              const float* __restrict__ Wa,
                                              const float* __restrict__ Wb,
                                              u16* __restrict__ Wbh,
                                              u16* __restrict__ Wbl) {
    const int k = blockIdx.x * 256 + threadIdx.x;  // 0..1535
    const int c = blockIdx.y;                      // 0..127
    float v = 0.f;
    if (c < 120)       v = Wih[c * (Dd + 1) + k];
    else if (c == 120) v = Wa[k];
    else if (c == 121) v = Wb[k];
    unsigned int u = __float_as_uint(v);
    unsigned int h = u & 0xffff0000u;
    float lo = v - __uint_as_float(h);
    Wbh[(size_t)c * Dd + k] = (u16)(u >> 16);
    Wbl[(size_t)c * Dd + k] = (u16)(__float_as_uint(lo) >> 16);
}

// ---------------- pack 3: single-wave scan weight table WS3[64][64] -----------
// lane l = 4q+g (q=l>>2, g=l&3, gate order i,f,g,o).
// slot0 (WS3[l][0..31]):  col c0 = g*30 + q          (q in [0,16))
//   j<30: Whh[c0][j];  [30] = Wih[c0][Dd] (z inject); [31] = 0
// slot1 (WS3[l][32..63]): col c1 = g*30 + 16 + q for q<14; lane56 = ax row
//   (Wa[Dd+j], inject 0), lane60 = bx row (Wb[Dd+j]); other q>=14 lanes: 0.
__global__ __launch_bounds__(64) void pack_s3(const float* __restrict__ Wih,
                                              const float* __restrict__ Whh,
                                              const float* __restrict__ Wa,
                                              const float* __restrict__ Wb,
                                              float* __restrict__ WS3) {
    const int l = threadIdx.x;        // 0..63
    const int q = l >> 2, g = l & 3;
    float v0[32], v1[32];
#pragma unroll
    for (int j = 0; j < 32; j++) { v0[j] = 0.f; v1[j] = 0.f; }
    {
        int c0 = g * 30 + q;          // q<16<30 -> always valid
        for (int j = 0; j < 30; j++) v0[j] = Whh[c0 * Hh + j];
        v0[30] = Wih[c0 * (Dd + 1) + Dd];
    }
    if (q < 14) {
        int c1 = g * 30 + 16 + q;
        for (int j = 0; j < 30; j++) v1[j] = Whh[c1 * Hh + j];
        v1[30] = Wih[c1 * (Dd + 1) + Dd];
    } else if (l == 56) {
        for (int j = 0; j < 30; j++) v1[j] = Wa[Dd + j];
    } else if (l == 60) {
        for (int j = 0; j < 30; j++) v1[j] = Wb[Dd + j];
    }
    float* dst = WS3 + (size_t)l * 64;
    for (int j = 0; j < 32; j++) { dst[j] = v0[j]; dst[32 + j] = v1[j]; }
}

// ---------------- gemm: GX[m][c] = X[m,:] @ W[:,c] + bias[c] (UNCHANGED) ------
__global__ __launch_bounds__(256, 2) void gemm_k(const float* __restrict__ X,
                                                 const u16* __restrict__ Wbh,
                                                 const u16* __restrict__ Wbl,
                                                 const float* __restrict__ bih,
                                                 const float* __restrict__ bhh,
                                                 const float* __restrict__ ba,
                                                 const float* __restrict__ bbp,
                                                 float* __restrict__ GX) {
    const int t    = threadIdx.x;
    const int lane = t & 63;
    const int wid  = t >> 6;
    const int wrow = wid >> 1;            // m half 0..1
    const int wcol = wid & 1;             // n half 0..1
    const int m0   = blockIdx.x * 64 + wrow * 32;
    const int n0   = wcol * 64;
    const int lr   = lane & 15;           // row-in-tile (A) / col-in-tile (B, C/D)
    const int lk   = lane >> 4;           // k-group 0..3 -> k offset lk*8

    const float* xa0 = X + (size_t)(m0 + lr) * Dd + lk * 8;
    const float* xa1 = xa0 + (size_t)16 * Dd;
    const u16*   pbh = Wbh + (size_t)(n0 + lr) * Dd + lk * 8;
    const u16*   pbl = Wbl + (size_t)(n0 + lr) * Dd + lk * 8;

    f32x4 acc[2][4];
#pragma unroll
    for (int nt = 0; nt < 4; nt++) {
        int c = n0 + nt * 16 + lr;
        float bv = (c < 120) ? (bih[c] + bhh[c])
                 : (c == 120) ? ba[0]
                 : (c == 121) ? bbp[0] : 0.f;
        f32x4 v = {bv, bv, bv, bv};
        acc[0][nt] = v;
        acc[1][nt] = v;
    }

#define LOADA(ra, ks) do {                                        \
        ra[0] = *(const float4*)(xa0 + (ks) * 32);                \
        ra[1] = *(const float4*)(xa0 + (ks) * 32 + 4);            \
        ra[2] = *(const float4*)(xa1 + (ks) * 32);                \
        ra[3] = *(const float4*)(xa1 + (ks) * 32 + 4);            \
    } while (0)

#define LOADB(bh, bl, ks) do {                                               \
        _Pragma("unroll")                                                    \
        for (int nt = 0; nt < 4; nt++) {                                     \
            bh[nt] = *(const short8v*)(pbh + (size_t)nt * 16 * Dd + (ks) * 32); \
            bl[nt] = *(const short8v*)(pbl + (size_t)nt * 16 * Dd + (ks) * 32); \
        }                                                                    \
    } while (0)

#define STEP(ra, bh, bl) do {                                     \
        short8v ah0, al0, ah1, al1;                               \
        cvt_split(ra[0], ra[1], ah0, al0);                        \
        cvt_split(ra[2], ra[3], ah1, al1);                        \
        _Pragma("unroll")                                         \
        for (int nt = 0; nt < 4; nt++)                            \
            acc[0][nt] = mm_bf16(ah0, bh[nt], acc[0][nt]);        \
        _Pragma("unroll")                                         \
        for (int nt = 0; nt < 4; nt++)                            \
            acc[1][nt] = mm_bf16(ah1, bh[nt], acc[1][nt]);        \
        _Pragma("unroll")                                         \
        for (int nt = 0; nt < 4; nt++)                            \
            acc[0][nt] = mm_bf16(al0, bh[nt], acc[0][nt]);        \
        _Pragma("unroll")                                         \
        for (int nt = 0; nt < 4; nt++)                            \
            acc[1][nt] = mm_bf16(al1, bh[nt], acc[1][nt]);        \
        _Pragma("unroll")                                         \
        for (int nt = 0; nt < 4; nt++)                            \
            acc[0][nt] = mm_bf16(ah0, bl[nt], acc[0][nt]);        \
        _Pragma("unroll")                                         \
        for (int nt = 0; nt < 4; nt++)                            \
            acc[1][nt] = mm_bf16(ah1, bl[nt], acc[1][nt]);        \
    } while (0)

    float4  ra0[4], ra1[4];
    short8v bh0[4], bl0[4], bh1[4], bl1[4];

    LOADA(ra0, 0);
    LOADB(bh0, bl0, 0);
    int ks = 0;
    for (; ks < KSTEPS - 2; ks += 2) {
        LOADA(ra1, ks + 1);
        LOADB(bh1, bl1, ks + 1);
        STEP(ra0, bh0, bl0);
        LOADA(ra0, ks + 2);
        LOADB(bh0, bl0, ks + 2);
        STEP(ra1, bh1, bl1);
    }
    LOADA(ra1, KSTEPS - 1);
    LOADB(bh1, bl1, KSTEPS - 1);
    STEP(ra0, bh0, bl0);
    STEP(ra1, bh1, bl1);

#undef LOADA
#undef LOADB
#undef STEP

    // C/D layout (m89-verified): col = lane&15, row = (lane>>4)*4 + reg
#pragma unroll
    for (int mt = 0; mt < 2; mt++)
#pragma unroll
        for (int nt = 0; nt < 4; nt++) {
            float* dst = GX + (size_t)(m0 + mt * 16 + lk * 4) * NC + n0 + nt * 16 + lr;
#pragma unroll
            for (int r = 0; r < 4; r++)
                dst[(size_t)r * NC] = acc[mt][nt][r];
        }
}

// pin 16 array elements into live VGPRs at this program point (zero instructions)
#define PIN16(A, B) asm volatile("" \
    : "+v"(A[B+0]), "+v"(A[B+1]), "+v"(A[B+2]),  "+v"(A[B+3]),  "+v"(A[B+4]),  "+v"(A[B+5]),  "+v"(A[B+6]),  "+v"(A[B+7]), \
      "+v"(A[B+8]), "+v"(A[B+9]), "+v"(A[B+10]), "+v"(A[B+11]), "+v"(A[B+12]), "+v"(A[B+13]), "+v"(A[B+14]), "+v"(A[B+15]))

// ---------------- scan v4: ONE wave per batch, zero LDS/barrier in the loop ---
// lane = 4q+g: slot0 = gate g of h-index q (q<16), slot1 = gate g of index 16+q
// (q<14); lanes 56/60 slot1 = ax/bx dots. i/f/g/o gather = DPP quad_perm (VALU,
// replaces 3 x ~120cyc ds_swizzle). h broadcast = 30 readlanes into SGPRs
// (replaces LDS write + barrier + LDS read). z-chain overlaps dot0 issue.
__global__
__attribute__((amdgpu_flat_work_group_size(64, 64)))
__attribute__((amdgpu_waves_per_eu(1)))
void scan_k(const float* __restrict__ u,
            const float* __restrict__ gx,
            const float* __restrict__ WS3,
            float* __restrict__ out) {
    __shared__ float lus[Tt];
    __shared__ float zbuf[Tt];
    const int b = blockIdx.x;
    const int l = threadIdx.x;
    const int q = l >> 2, g = l & 3;

    for (int k = l; k < Tt; k += 64) {
        float uu = u[b * Tt + k];
        uu = fminf(fmaxf(uu, 1e-5f), 1.f - 1e-5f);
        lus[k] = __logf(1.f - uu);
    }
    __syncthreads();

    // per-lane weights: slot0 + slot1, 64 floats -> VGPRs
    float wv0[32], wv1[32];
    {
        const float* wp = WS3 + (size_t)l * 64;
#pragma unroll
        for (int j = 0; j < 8; j++) {
            float4 a4 = ((const float4*)wp)[j];
            float4 b4 = ((const float4*)(wp + 32))[j];
            wv0[4 * j + 0] = a4.x; wv0[4 * j + 1] = a4.y;
            wv0[4 * j + 2] = a4.z; wv0[4 * j + 3] = a4.w;
            wv1[4 * j + 0] = b4.x; wv1[4 * j + 1] = b4.y;
            wv1[4 * j + 2] = b4.z; wv1[4 * j + 3] = b4.w;
        }
    }

    // gx columns for the two slots
    const int c0 = g * 30 + q;
    const int c1 = (q < 14) ? (g * 30 + 16 + q) : ((l == 56) ? 120 : (l == 60) ? 121 : 124);
    const float* p0 = gx + (size_t)b * Tt * NC + c0;
    const float* p1 = gx + (size_t)b * Tt * NC + c1;

    // h state: uniform values (readlane results) -> SGPRs
    float hs[Hh];
#pragma unroll
    for (int k = 0; k < Hh; k++) hs[k] = 0.f;
    float cst0 = 0.f, cst1 = 0.f;

    // depth-2 prefetch pipeline
    float A0 = p0[0], B0 = p1[0];
    float A1 = p0[NC], B1 = p1[NC];
    float lu0 = lus[0], lu1 = lus[1];

    for (int t = 0; t < Tt; t++) {
        PIN16(wv0, 0); PIN16(wv0, 16);
        PIN16(wv1, 0); PIN16(wv1, 16);

        // ---- slot1 dot first (feeds the z-chain via lanes 56/60) ----
        float d10 = B0, d11 = 0.f, d12 = 0.f, d13 = 0.f;
#pragma unroll
        for (int k = 0; k < 28; k += 4) {
            d10 = fmaf(wv1[k], hs[k], d10);         d11 = fmaf(wv1[k + 1], hs[k + 1], d11);
            d12 = fmaf(wv1[k + 2], hs[k + 2], d12); d13 = fmaf(wv1[k + 3], hs[k + 3], d13);
        }
        d10 = fmaf(wv1[28], hs[28], d10); d11 = fmaf(wv1[29], hs[29], d11);
        float dot1 = (d10 + d12) + (d11 + d13);

        // ---- z-chain (uniform); dot0 issues under these stalls ----
        const float av = rl_f(dot1, 56);
        const float bv = rl_f(dot1, 60);
        float a  = fminf(fmaxf(softplus_(av), 1e-6f), 100.f);
        float bk = fminf(fmaxf(softplus_(bv), 1e-6f), 100.f);
        float lu = lu0;
        float p = __expf(lu * rcpf_(bk));
        float inner = 1.f - p;
        float s = (inner <= 0.f) ? 0.f : __expf(__logf(inner) * rcpf_(a));
        float z = fminf(fmaxf(fmaf(1.2f, s, -0.1f), 0.f), 1.f);

        // ---- slot0 dot (independent of z until inject) ----
        float d00 = A0, d01 = 0.f, d02 = 0.f, d03 = 0.f;
#pragma unroll
        for (int k = 0; k < 28; k += 4) {
            d00 = fmaf(wv0[k], hs[k], d00);         d01 = fmaf(wv0[k + 1], hs[k + 1], d01);
            d02 = fmaf(wv0[k + 2], hs[k + 2], d02); d03 = fmaf(wv0[k + 3], hs[k + 3], d03);
        }
        d00 = fmaf(wv0[28], hs[28], d00); d01 = fmaf(wv0[29], hs[29], d01);
        float dot0 = (d00 + d02) + (d01 + d03);

        // rotate prefetch, fetch t+2 (off critical path)
        A0 = A1; B0 = B1; lu0 = lu1;
        if (t + 2 < Tt) {
            A1 = p0[(size_t)(t + 2) * NC];
            B1 = p1[(size_t)(t + 2) * NC];
            lu1 = lus[t + 2];
        }

        // inject z * Wih[:,D]
        float acc0 = fmaf(z, wv0[30], dot0);
        float acc1 = fmaf(z, wv1[30], dot1);

        // nonlinearity: tanh on g-gate lanes (g==2), sigmoid elsewhere
        float val0 = (g == 2) ? tanhf_fast(acc0) : sigmoidf_(acc0);
        float val1 = (g == 2) ? tanhf_fast(acc1) : sigmoidf_(acc1);

        // gather f,g,o onto i-lanes via DPP quad_perm (pure VALU)
        float vf0 = QPERM(val0, 0x55), vg0 = QPERM(val0, 0xAA), vo0 = QPERM(val0, 0xFF);
        float vf1 = QPERM(val1, 0x55), vg1 = QPERM(val1, 0xAA), vo1 = QPERM(val1, 0xFF);

        // LSTM combine on i-lanes (g==0): cn = sig(f)*c + sig(i)*tanh(g)
        float cn0 = fmaf(vf0, cst0, val0 * vg0);
        float hn0 = vo0 * tanhf_fast(cn0);
        cst0 = cn0;
        float cn1 = fmaf(vf1, cst1, val1 * vg1);
        float hn1 = vo1 * tanhf_fast(cn1);
        cst1 = cn1;

        // broadcast h to uniform (SGPR) state: slot0 -> h[0..16), slot1 -> h[16..30)
#pragma unroll
        for (int k = 0; k < 16; k++) hs[k] = rl_f(hn0, 4 * k);
#pragma unroll
        for (int k = 16; k < Hh; k++) hs[k] = rl_f(hn1, 4 * (k - 16));

        if (l == 0) zbuf[t] = z;
    }
    __syncthreads();
    for (int k = l; k < Tt; k += 64) out[b * Tt + k] = zbuf[k];
}

extern "C" void kernel_launch(void* const* d_in, const int* in_sizes, int n_in,
                              void* d_out, int out_size, void* d_ws, size_t ws_size,
                              hipStream_t stream) {
    const float* x   = (const float*)d_in[0];
    const float* u   = (const float*)d_in[1];
    const float* Wih = (const float*)d_in[2];
    const float* Whh = (const float*)d_in[3];
    const float* bih = (const float*)d_in[4];
    const float* bhh = (const float*)d_in[5];
    const float* Wa  = (const float*)d_in[6];
    const float* ba  = (const float*)d_in[7];
    const float* Wb  = (const float*)d_in[8];
    const float* bbp = (const float*)d_in[9];
    float* out = (float*)d_out;

    // ws layout (bytes):
    char* wsb = (char*)d_ws;
    u16*   Wbh = (u16*)(wsb);                    // 128*1536*2 = 393216
    u16*   Wbl = (u16*)(wsb + 393216);           // 393216
    float* WS3 = (float*)(wsb + 786432);         // 64*64*4 = 16384
    float* GX  = (float*)(wsb + 802816);         // 32768*128*4 = 16777216

    pack_w<<<dim3(Dd / 256, NC), 256, 0, stream>>>(Wih, Wa, Wb, Wbh, Wbl);
    pack_s3<<<1, 64, 0, stream>>>(Wih, Whh, Wa, Wb, WS3);
    gemm_k<<<Mm / 64, 256, 0, stream>>>(x, Wbh, Wbl, bih, bhh, ba, bbp, GX);
    scan_k<<<Bb, 64, 0, stream>>>(u, GX, WS3, out);
}

// Round 6
// 649.481 us; speedup vs baseline: 1.0260x; 1.0260x over previous
//
#include <hip/hip_runtime.h>
#include <math.h>

#define Bb 64
#define Tt 512
#define Dd 1536
#define Hh 30
#define NC 128            // packed GX cols: gate layout unchanged
#define Mm (Bb*Tt)        // 32768 rows
#define KSTEPS 48         // 1536 / 32

typedef unsigned short u16;
typedef __attribute__((ext_vector_type(8))) short short8v;  // 8 bf16 = 4 VGPRs
typedef __attribute__((ext_vector_type(4))) float f32x4;

__device__ __forceinline__ float rcpf_(float x) { return __builtin_amdgcn_rcpf(x); }
__device__ __forceinline__ float sigmoidf_(float x) {
    return rcpf_(1.f + __expf(-x));
}
__device__ __forceinline__ float tanhf_fast(float x) {
    float e = __expf(2.f * x);
    return fmaf(-2.f, rcpf_(e + 1.f), 1.f);
}
__device__ __forceinline__ float softplus_(float x) {
    return fmaxf(x, 0.f) + __logf(1.f + __expf(-fabsf(x)));
}
__device__ __forceinline__ float rl_f(float v, int lane) {
    return __uint_as_float(__builtin_amdgcn_readlane(__float_as_uint(v), lane));
}

// DPP quad_perm broadcast within each 4-lane group (pure VALU, ~4 cyc):
// CTRL 0x55 = all lanes read quad-lane 1, 0xAA -> lane 2, 0xFF -> lane 3.
#define QPERM(src, CTRL) \
    __uint_as_float((unsigned)__builtin_amdgcn_mov_dpp((int)__float_as_uint(src), CTRL, 0xF, 0xF, false))

// async global->LDS, 16B per lane: lane i lands at ldsbase + i*16 (linear)
#define GLOAD_LDS16(gp, lp) \
    __builtin_amdgcn_global_load_lds((const __attribute__((address_space(1))) void*)(const void*)(gp), \
                                     (__attribute__((address_space(3))) void*)(void*)(lp), 16, 0, 0)

__device__ __forceinline__ f32x4 mm_bf16(short8v a, short8v b, f32x4 c) {
    return __builtin_amdgcn_mfma_f32_16x16x32_bf16(a, b, c, 0, 0, 0);
}

union U4S8 { unsigned int u[4]; short8v s; };

// exact hi/lo split: x = hi + lo with hi = trunc-bf16(x)
__device__ __forceinline__ void cvt_split(const float4 a, const float4 b,
                                          short8v& hi, short8v& lo) {
    float x[8] = {a.x, a.y, a.z, a.w, b.x, b.y, b.z, b.w};
    U4S8 H, L;
#pragma unroll
    for (int i = 0; i < 4; i++) {
        unsigned int u0 = __float_as_uint(x[2 * i]);
        unsigned int u1 = __float_as_uint(x[2 * i + 1]);
        unsigned int h0 = u0 & 0xffff0000u;
        unsigned int h1 = u1 & 0xffff0000u;
        H.u[i] = (u0 >> 16) | h1;
        float l0 = x[2 * i]     - __uint_as_float(h0);
        float l1 = x[2 * i + 1] - __uint_as_float(h1);
        L.u[i] = (__float_as_uint(l0) >> 16) | (__float_as_uint(l1) & 0xffff0000u);
    }
    hi = H.s;
    lo = L.s;
}

// ---------------- pack 1: W -> bf16 hi/lo, col-major Wb*[c][k] ----------------
__global__ __launch_bounds__(256) void pack_w(const float* __restrict__ Wih,
                                              const float* __restrict__ Wa,
                                              const float* __restrict__ Wb,
                                              u16* __restrict__ Wbh,
                                              u16* __restrict__ Wbl) {
    const int k = blockIdx.x * 256 + threadIdx.x;  // 0..1535
    const int c = blockIdx.y;                      // 0..127
    float v = 0.f;
    if (c < 120)       v = Wih[c * (Dd + 1) + k];
    else if (c == 120) v = Wa[k];
    else if (c == 121) v = Wb[k];
    unsigned int u = __float_as_uint(v);
    unsigned int h = u & 0xffff0000u;
    float lo = v - __uint_as_float(h);
    Wbh[(size_t)c * Dd + k] = (u16)(u >> 16);
    Wbl[(size_t)c * Dd + k] = (u16)(__float_as_uint(lo) >> 16);
}

// ---------------- pack 3: single-wave scan weight table WS3[64][64] -----------
// lane l = 4q+g (q=l>>2, g=l&3, gate order i,f,g,o).
// slot0 (WS3[l][0..31]):  col c0 = g*30 + q          (q in [0,16))
//   j<30: Whh[c0][j];  [30] = Wih[c0][Dd] (z inject); [31] = 0
// slot1 (WS3[l][32..63]): col c1 = g*30 + 16 + q for q<14; lane56 = ax row
//   (Wa[Dd+j], inject 0), lane60 = bx row (Wb[Dd+j]); other q>=14 lanes: 0.
__global__ __launch_bounds__(64) void pack_s3(const float* __restrict__ Wih,
                                              const float* __restrict__ Whh,
                                              const float* __restrict__ Wa,
                                              const float* __restrict__ Wb,
                                              float* __restrict__ WS3) {
    const int l = threadIdx.x;        // 0..63
    const int q = l >> 2, g = l & 3;
    float v0[32], v1[32];
#pragma unroll
    for (int j = 0; j < 32; j++) { v0[j] = 0.f; v1[j] = 0.f; }
    {
        int c0 = g * 30 + q;          // q<16<30 -> always valid
        for (int j = 0; j < 30; j++) v0[j] = Whh[c0 * Hh + j];
        v0[30] = Wih[c0 * (Dd + 1) + Dd];
    }
    if (q < 14) {
        int c1 = g * 30 + 16 + q;
        for (int j = 0; j < 30; j++) v1[j] = Whh[c1 * Hh + j];
        v1[30] = Wih[c1 * (Dd + 1) + Dd];
    } else if (l == 56) {
        for (int j = 0; j < 30; j++) v1[j] = Wa[Dd + j];
    } else if (l == 60) {
        for (int j = 0; j < 30; j++) v1[j] = Wb[Dd + j];
    }
    float* dst = WS3 + (size_t)l * 64;
    for (int j = 0; j < 32; j++) { dst[j] = v0[j]; dst[32 + j] = v1[j]; }
}

// ---------------- gemm: GX[m][c] = X[m,:] @ W[:,c] + bias[c] (UNCHANGED) ------
__global__ __launch_bounds__(256, 2) void gemm_k(const float* __restrict__ X,
                                                 const u16* __restrict__ Wbh,
                                                 const u16* __restrict__ Wbl,
                                                 const float* __restrict__ bih,
                                                 const float* __restrict__ bhh,
                                                 const float* __restrict__ ba,
                                                 const float* __restrict__ bbp,
                                                 float* __restrict__ GX) {
    const int t    = threadIdx.x;
    const int lane = t & 63;
    const int wid  = t >> 6;
    const int wrow = wid >> 1;            // m half 0..1
    const int wcol = wid & 1;             // n half 0..1
    const int m0   = blockIdx.x * 64 + wrow * 32;
    const int n0   = wcol * 64;
    const int lr   = lane & 15;           // row-in-tile (A) / col-in-tile (B, C/D)
    const int lk   = lane >> 4;           // k-group 0..3 -> k offset lk*8

    const float* xa0 = X + (size_t)(m0 + lr) * Dd + lk * 8;
    const float* xa1 = xa0 + (size_t)16 * Dd;
    const u16*   pbh = Wbh + (size_t)(n0 + lr) * Dd + lk * 8;
    const u16*   pbl = Wbl + (size_t)(n0 + lr) * Dd + lk * 8;

    f32x4 acc[2][4];
#pragma unroll
    for (int nt = 0; nt < 4; nt++) {
        int c = n0 + nt * 16 + lr;
        float bv = (c < 120) ? (bih[c] + bhh[c])
                 : (c == 120) ? ba[0]
                 : (c == 121) ? bbp[0] : 0.f;
        f32x4 v = {bv, bv, bv, bv};
        acc[0][nt] = v;
        acc[1][nt] = v;
    }

#define LOADA(ra, ks) do {                                        \
        ra[0] = *(const float4*)(xa0 + (ks) * 32);                \
        ra[1] = *(const float4*)(xa0 + (ks) * 32 + 4);            \
        ra[2] = *(const float4*)(xa1 + (ks) * 32);                \
        ra[3] = *(const float4*)(xa1 + (ks) * 32 + 4);            \
    } while (0)

#define LOADB(bh, bl, ks) do {                                               \
        _Pragma("unroll")                                                    \
        for (int nt = 0; nt < 4; nt++) {                                     \
            bh[nt] = *(const short8v*)(pbh + (size_t)nt * 16 * Dd + (ks) * 32); \
            bl[nt] = *(const short8v*)(pbl + (size_t)nt * 16 * Dd + (ks) * 32); \
        }                                                                    \
    } while (0)

#define STEP(ra, bh, bl) do {                                     \
        short8v ah0, al0, ah1, al1;                               \
        cvt_split(ra[0], ra[1], ah0, al0);                        \
        cvt_split(ra[2], ra[3], ah1, al1);                        \
        _Pragma("unroll")                                         \
        for (int nt = 0; nt < 4; nt++)                            \
            acc[0][nt] = mm_bf16(ah0, bh[nt], acc[0][nt]);        \
        _Pragma("unroll")                                         \
        for (int nt = 0; nt < 4; nt++)                            \
            acc[1][nt] = mm_bf16(ah1, bh[nt], acc[1][nt]);        \
        _Pragma("unroll")                                         \
        for (int nt = 0; nt < 4; nt++)                            \
            acc[0][nt] = mm_bf16(al0, bh[nt], acc[0][nt]);        \
        _Pragma("unroll")                                         \
        for (int nt = 0; nt < 4; nt++)                            \
            acc[1][nt] = mm_bf16(al1, bh[nt], acc[1][nt]);        \
        _Pragma("unroll")                                         \
        for (int nt = 0; nt < 4; nt++)                            \
            acc[0][nt] = mm_bf16(ah0, bl[nt], acc[0][nt]);        \
        _Pragma("unroll")                                         \
        for (int nt = 0; nt < 4; nt++)                            \
            acc[1][nt] = mm_bf16(ah1, bl[nt], acc[1][nt]);        \
    } while (0)

    float4  ra0[4], ra1[4];
    short8v bh0[4], bl0[4], bh1[4], bl1[4];

    LOADA(ra0, 0);
    LOADB(bh0, bl0, 0);
    int ks = 0;
    for (; ks < KSTEPS - 2; ks += 2) {
        LOADA(ra1, ks + 1);
        LOADB(bh1, bl1, ks + 1);
        STEP(ra0, bh0, bl0);
        LOADA(ra0, ks + 2);
        LOADB(bh0, bl0, ks + 2);
        STEP(ra1, bh1, bl1);
    }
    LOADA(ra1, KSTEPS - 1);
    LOADB(bh1, bl1, KSTEPS - 1);
    STEP(ra0, bh0, bl0);
    STEP(ra1, bh1, bl1);

#undef LOADA
#undef LOADB
#undef STEP

    // C/D layout (m89-verified): col = lane&15, row = (lane>>4)*4 + reg
#pragma unroll
    for (int mt = 0; mt < 2; mt++)
#pragma unroll
        for (int nt = 0; nt < 4; nt++) {
            float* dst = GX + (size_t)(m0 + mt * 16 + lk * 4) * NC + n0 + nt * 16 + lr;
#pragma unroll
            for (int r = 0; r < 4; r++)
                dst[(size_t)r * NC] = acc[mt][nt][r];
        }
}

// pin 16 array elements into live VGPRs at this program point (zero instructions)
#define PIN16(A, B) asm volatile("" \
    : "+v"(A[B+0]), "+v"(A[B+1]), "+v"(A[B+2]),  "+v"(A[B+3]),  "+v"(A[B+4]),  "+v"(A[B+5]),  "+v"(A[B+6]),  "+v"(A[B+7]), \
      "+v"(A[B+8]), "+v"(A[B+9]), "+v"(A[B+10]), "+v"(A[B+11]), "+v"(A[B+12]), "+v"(A[B+13]), "+v"(A[B+14]), "+v"(A[B+15]))

// ---------------- scan v5: v4 compute + LDS chunk-staged GX -------------------
// v3/v4 both stuck at ~1270 cyc/step: GX per-lane loads (4B scattered, stride
// 512B) had only 1 step of prefetch slack vs ~900cyc L2-miss latency. v5 stages
// GX in contiguous 16KB chunks (32 rows) via global_load_lds, double-buffered:
// slack = 32 steps. In-loop loads become 2 ds_read_b32 (row t+1, 1-step reg
// prefetch). Single wave -> no barriers; one vmcnt(0) per 32 steps.
__global__
__attribute__((amdgpu_flat_work_group_size(64, 64)))
__attribute__((amdgpu_waves_per_eu(1)))
void scan_k(const float* __restrict__ u,
            const float* __restrict__ gx,
            const float* __restrict__ WS3,
            float* __restrict__ out) {
    __shared__ float lus[Tt];
    __shared__ float zbuf[Tt];
    __shared__ float gxs[2][32][NC];     // 32 KB chunk double-buffer
    const int b = blockIdx.x;
    const int l = threadIdx.x;
    const int q = l >> 2, g = l & 3;

    for (int k = l; k < Tt; k += 64) {
        float uu = u[b * Tt + k];
        uu = fminf(fmaxf(uu, 1e-5f), 1.f - 1e-5f);
        lus[k] = __logf(1.f - uu);
    }
    __syncthreads();

    // per-lane weights: slot0 + slot1, 64 floats -> VGPRs
    float wv0[32], wv1[32];
    {
        const float* wp = WS3 + (size_t)l * 64;
#pragma unroll
        for (int j = 0; j < 8; j++) {
            float4 a4 = ((const float4*)wp)[j];
            float4 b4 = ((const float4*)(wp + 32))[j];
            wv0[4 * j + 0] = a4.x; wv0[4 * j + 1] = a4.y;
            wv0[4 * j + 2] = a4.z; wv0[4 * j + 3] = a4.w;
            wv1[4 * j + 0] = b4.x; wv1[4 * j + 1] = b4.y;
            wv1[4 * j + 2] = b4.z; wv1[4 * j + 3] = b4.w;
        }
    }

    // gx columns for the two slots
    const int c0 = g * 30 + q;
    const int c1 = (q < 14) ? (g * 30 + 16 + q) : ((l == 56) ? 120 : (l == 60) ? 121 : 124);
    const float* gxb0 = gx + (size_t)b * Tt * NC;

    // nonlin input multiplier: tanh lanes (g==2) use exp(2x), others exp(-x)
    const float mge = (g == 2) ? 2.f : -1.f;

    // h state: uniform values (readlane results) -> SGPRs
    float hs[Hh];
#pragma unroll
    for (int k = 0; k < Hh; k++) hs[k] = 0.f;
    float cst0 = 0.f, cst1 = 0.f;

    // stage chunk 0, wait, read row 0
#pragma unroll
    for (int j = 0; j < 16; j++)
        GLOAD_LDS16(gxb0 + j * 256 + l * 4, &gxs[0][0][0] + j * 256);
    asm volatile("s_waitcnt vmcnt(0)" ::: "memory");
    float A0 = gxs[0][0][c0], B0 = gxs[0][0][c1], L0 = lus[0];

    for (int c = 0; c < Tt / 32; c++) {
        if (c < Tt / 32 - 1) {
            const float* gch = gxb0 + (size_t)(c + 1) * 32 * NC;
            float* lch = &gxs[(c + 1) & 1][0][0];
#pragma unroll
            for (int j = 0; j < 16; j++)
                GLOAD_LDS16(gch + j * 256 + l * 4, lch + j * 256);
        }
#pragma unroll 1
        for (int s = 0; s < 32; s++) {
            const int t = c * 32 + s;
            PIN16(wv0, 0); PIN16(wv0, 16);
            PIN16(wv1, 0); PIN16(wv1, 16);

            // ---- prefetch row t+1 into regs (LDS, latency hidden by step) ----
            float A1 = 0.f, B1 = 0.f, L1 = 0.f;
            if (t + 1 < Tt) {
                if (s < 31) {
                    A1 = gxs[c & 1][s + 1][c0];
                    B1 = gxs[c & 1][s + 1][c1];
                } else {
                    asm volatile("s_waitcnt vmcnt(0)" ::: "memory");  // chunk c+1 resident
                    A1 = gxs[(c + 1) & 1][0][c0];
                    B1 = gxs[(c + 1) & 1][0][c1];
                }
                L1 = lus[t + 1];
            }

            // ---- slot1 dot first (feeds the z-chain via lanes 56/60) ----
            float d10 = B0, d11 = 0.f, d12 = 0.f, d13 = 0.f;
#pragma unroll
            for (int k = 0; k < 28; k += 4) {
                d10 = fmaf(wv1[k], hs[k], d10);         d11 = fmaf(wv1[k + 1], hs[k + 1], d11);
                d12 = fmaf(wv1[k + 2], hs[k + 2], d12); d13 = fmaf(wv1[k + 3], hs[k + 3], d13);
            }
            d10 = fmaf(wv1[28], hs[28], d10); d11 = fmaf(wv1[29], hs[29], d11);
            float dot1 = (d10 + d12) + (d11 + d13);

            // ---- z-chain (uniform); dot0 issues under these stalls ----
            const float av = rl_f(dot1, 56);
            const float bv = rl_f(dot1, 60);
            float a  = fminf(fmaxf(softplus_(av), 1e-6f), 100.f);
            float bk = fminf(fmaxf(softplus_(bv), 1e-6f), 100.f);
            float lu = L0;
            float p = __expf(lu * rcpf_(bk));
            float inner = 1.f - p;
            float sK = (inner <= 0.f) ? 0.f : __expf(__logf(inner) * rcpf_(a));
            float z = fminf(fmaxf(fmaf(1.2f, sK, -0.1f), 0.f), 1.f);

            // ---- slot0 dot (independent of z until inject) ----
            float d00 = A0, d01 = 0.f, d02 = 0.f, d03 = 0.f;
#pragma unroll
            for (int k = 0; k < 28; k += 4) {
                d00 = fmaf(wv0[k], hs[k], d00);         d01 = fmaf(wv0[k + 1], hs[k + 1], d01);
                d02 = fmaf(wv0[k + 2], hs[k + 2], d02); d03 = fmaf(wv0[k + 3], hs[k + 3], d03);
            }
            d00 = fmaf(wv0[28], hs[28], d00); d01 = fmaf(wv0[29], hs[29], d01);
            float dot0 = (d00 + d02) + (d01 + d03);

            // inject z * Wih[:,D]
            float acc0 = fmaf(z, wv0[30], dot0);
            float acc1 = fmaf(z, wv1[30], dot1);

            // nonlinearity: shared exp+rcp, select per lane
            // g==2: tanh(x)=1-2/(e^{2x}+1);  else: sigmoid(x)=1/(1+e^{-x})
            float e0 = __expf(acc0 * mge);
            float e1 = __expf(acc1 * mge);
            float r0 = rcpf_(1.f + e0);
            float r1 = rcpf_(1.f + e1);
            float val0 = (g == 2) ? fmaf(-2.f, r0, 1.f) : r0;
            float val1 = (g == 2) ? fmaf(-2.f, r1, 1.f) : r1;

            // gather f,g,o onto i-lanes via DPP quad_perm (pure VALU)
            float vf0 = QPERM(val0, 0x55), vg0 = QPERM(val0, 0xAA), vo0 = QPERM(val0, 0xFF);
            float vf1 = QPERM(val1, 0x55), vg1 = QPERM(val1, 0xAA), vo1 = QPERM(val1, 0xFF);

            // LSTM combine on i-lanes (g==0): cn = sig(f)*c + sig(i)*tanh(g)
            float cn0 = fmaf(vf0, cst0, val0 * vg0);
            float hn0 = vo0 * tanhf_fast(cn0);
            cst0 = cn0;
            float cn1 = fmaf(vf1, cst1, val1 * vg1);
            float hn1 = vo1 * tanhf_fast(cn1);
            cst1 = cn1;

            // broadcast h: slot0 -> h[0..16), slot1 -> h[16..30)
#pragma unroll
            for (int k = 0; k < 16; k++) hs[k] = rl_f(hn0, 4 * k);
#pragma unroll
            for (int k = 16; k < Hh; k++) hs[k] = rl_f(hn1, 4 * (k - 16));

            if (l == 0) zbuf[t] = z;
            A0 = A1; B0 = B1; L0 = L1;
        }
    }
    __syncthreads();
    for (int k = l; k < Tt; k += 64) out[b * Tt + k] = zbuf[k];
}

extern "C" void kernel_launch(void* const* d_in, const int* in_sizes, int n_in,
                              void* d_out, int out_size, void* d_ws, size_t ws_size,
                              hipStream_t stream) {
    const float* x   = (const float*)d_in[0];
    const float* u   = (const float*)d_in[1];
    const float* Wih = (const float*)d_in[2];
    const float* Whh = (const float*)d_in[3];
    const float* bih = (const float*)d_in[4];
    const float* bhh = (const float*)d_in[5];
    const float* Wa  = (const float*)d_in[6];
    const float* ba  = (const float*)d_in[7];
    const float* Wb  = (const float*)d_in[8];
    const float* bbp = (const float*)d_in[9];
    float* out = (float*)d_out;

    // ws layout (bytes):
    char* wsb = (char*)d_ws;
    u16*   Wbh = (u16*)(wsb);                    // 128*1536*2 = 393216
    u16*   Wbl = (u16*)(wsb + 393216);           // 393216
    float* WS3 = (float*)(wsb + 786432);         // 64*64*4 = 16384
    float* GX  = (float*)(wsb + 802816);         // 32768*128*4 = 16777216

    pack_w<<<dim3(Dd / 256, NC), 256, 0, stream>>>(Wih, Wa, Wb, Wbh, Wbl);
    pack_s3<<<1, 64, 0, stream>>>(Wih, Whh, Wa, Wb, WS3);
    gemm_k<<<Mm / 64, 256, 0, stream>>>(x, Wbh, Wbl, bih, bhh, ba, bbp, GX);
    scan_k<<<Bb, 64, 0, stream>>>(u, GX, WS3, out);
}